// Round 10
// baseline (205.892 us; speedup 1.0000x reference)
//
#include <hip/hip_runtime.h>
#include <cmath>

typedef unsigned int uint;
typedef unsigned short u16;

constexpr int N  = 131072;    // nodes
constexpr int E  = 4194304;   // edges (without self-loops)
constexpr int F  = 16;        // hidden width H1
constexpr int NB = 512;       // dst buckets of 256 nodes (bucket = dst>>8)
constexpr int NBLK  = 512;    // scatter blocks
constexpr int SCT   = 512;    // threads per block (scatter/gather/l1/l2)
constexpr int CHUNK = 8192;   // edges per scatter block (NBLK*CHUNK == E)
constexpr int EPT   = 16;     // edges per thread in scatter
constexpr int CAPB  = 9216;   // padded per-bucket region (mean 8192, sd ~90 -> 11 sd)

// ---- Phase A: block-local bucket grouping, private regions, coalesced ------
// Block g groups its 8192 edges by bucket in LDS, writes them to
// part[g*CHUNK ...] fully coalesced, and emits a directory:
//   cnt16[b*NBLK+g] = #edges of bucket b in block g
//   dir16[b*NBLK+g] = local offset of bucket b's run inside block g's region
__global__ void __launch_bounds__(SCT) k_scatter(
        const int* __restrict__ src, const int* __restrict__ dst,
        uint* __restrict__ part, u16* __restrict__ cnt16, u16* __restrict__ dir16) {
    __shared__ uint h[NB];          // hist -> bump counters
    __shared__ uint wsum[8];
    __shared__ uint vals[CHUNK];    // 32 KB staging
    int t = threadIdx.x, g = blockIdx.x;
    int lane = t & 63, w = t >> 6;
    h[t] = 0;
    __syncthreads();
    int d[EPT], s[EPT];
    const int4* src4 = (const int4*)src;
    const int4* dst4 = (const int4*)dst;
    int base4 = g * (CHUNK / 4);
#pragma unroll
    for (int k = 0; k < EPT / 4; ++k) {
        int4 d4 = dst4[base4 + k * SCT + t];
        int4 s4 = src4[base4 + k * SCT + t];
        d[4 * k + 0] = d4.x; d[4 * k + 1] = d4.y; d[4 * k + 2] = d4.z; d[4 * k + 3] = d4.w;
        s[4 * k + 0] = s4.x; s[4 * k + 1] = s4.y; s[4 * k + 2] = s4.z; s[4 * k + 3] = s4.w;
        atomicAdd(&h[d4.x >> 8], 1u);
        atomicAdd(&h[d4.y >> 8], 1u);
        atomicAdd(&h[d4.z >> 8], 1u);
        atomicAdd(&h[d4.w >> 8], 1u);
    }
    __syncthreads();
    uint v = h[t];
    uint sv = v;                                  // wave-level inclusive scan
#pragma unroll
    for (int off = 1; off < 64; off <<= 1) {
        uint n = __shfl_up(sv, off);
        if (lane >= off) sv += n;
    }
    if (lane == 63) wsum[w] = sv;
    __syncthreads();
    uint wo = 0;
    for (int i = 0; i < w; ++i) wo += wsum[i];
    sv += wo;                                     // inclusive over 512 buckets
    uint ex = sv - v;                             // local exclusive offset
    cnt16[(size_t)t * NBLK + g] = (u16)v;         // directory (bucket t, block g)
    dir16[(size_t)t * NBLK + g] = (u16)ex;
    __syncthreads();                              // all reads of h done
    h[t] = ex;                                    // bump starts at excl
    __syncthreads();
#pragma unroll
    for (int k = 0; k < EPT; ++k) {
        int b = d[k] >> 8;
        uint slot = atomicAdd(&h[b], 1u);
        vals[slot] = ((uint)s[k] << 8) | (uint)(d[k] & 255);
    }
    __syncthreads();
    uint4* part4 = (uint4*)(part + (size_t)g * CHUNK);
    const uint4* vals4 = (const uint4*)vals;
#pragma unroll
    for (int k = 0; k < EPT / 4; ++k)             // fully coalesced 16B stores
        part4[k * SCT + t] = vals4[k * SCT + t];
}

// ---- Phase B: coalesced directory gather -> part2 (bucket-contiguous), -----
// node degrees (bin counts), dinv, y = dinv*x. Output slot i binary-searches
// the 512-segment prefix so consecutive threads read consecutive addresses.
__global__ void __launch_bounds__(SCT) k_gather(
        const uint* __restrict__ part, const u16* __restrict__ cnt16,
        const u16* __restrict__ dir16, const float* __restrict__ x,
        uint* __restrict__ part2, uint* __restrict__ blen,
        float* __restrict__ dinv, float2* __restrict__ y) {
    __shared__ uint ps[NB + 1];     // exclusive prefix of segment lengths
    __shared__ uint segoff[NB];     // global offset of each segment
    __shared__ uint hw[8 * 256];    // wave-private node-bin counters (8 KB)
    __shared__ uint wsum[8];
    __shared__ uint stage[CAPB];    // 36 KB
    int t = threadIdx.x, b = blockIdx.x;
    int lane = t & 63, w = t >> 6;
#pragma unroll
    for (int k = 0; k < 4; ++k) hw[k * SCT + t] = 0;
    uint len = cnt16[(size_t)b * NBLK + t];
    segoff[t] = (uint)t * CHUNK + dir16[(size_t)b * NBLK + t];
    uint sv = len;                                // shfl inclusive scan
#pragma unroll
    for (int off = 1; off < 64; off <<= 1) {
        uint n = __shfl_up(sv, off);
        if (lane >= off) sv += n;
    }
    if (lane == 63) wsum[w] = sv;
    __syncthreads();
    uint wo = 0;
    for (int i = 0; i < w; ++i) wo += wsum[i];
    ps[t] = sv + wo - len;                        // exclusive prefix
    uint L = 0;
#pragma unroll
    for (int i = 0; i < 8; ++i) L += wsum[i];
    if (t == 0) ps[NB] = L;
    __syncthreads();
    for (uint i = t; i < L; i += SCT) {           // coalesced gather + count
        uint lo = 0, hi = NB;                     // find max s: ps[s] <= i
        while (hi - lo > 1) {
            uint mid = (lo + hi) >> 1;
            if (ps[mid] <= i) lo = mid; else hi = mid;
        }
        uint pk = part[segoff[lo] + (i - ps[lo])];
        if (i < (uint)CAPB) stage[i] = pk;
        atomicAdd(&hw[w * 256 + (pk & 255u)], 1u);
    }
    __syncthreads();
    uint Lc = (L > (uint)CAPB) ? (uint)CAPB : L;
    uint* o2 = part2 + (size_t)b * CAPB;
    for (uint i = t; i < Lc; i += SCT) o2[i] = stage[i];   // coalesced flush
    if (t == 0) blen[b] = Lc;
    if (t < 256) {
        uint c = 0;
#pragma unroll
        for (int k = 0; k < 8; ++k) c += hw[k * 256 + t];
        int node = (b << 8) + t;
        float di = rsqrtf(1.0f + (float)c);       // +1 self-loop
        dinv[node] = di;
        float2 xv = ((const float2*)x)[node];
        y[node] = make_float2(di * xv.x, di * xv.y);
    }
}

// ---- layer 1: streaming bucket pass, wave-private LDS float bins + MLP -----
__global__ void __launch_bounds__(SCT) k_l1(
        const uint* __restrict__ part2, const uint* __restrict__ blen,
        const float2* __restrict__ y, const float* __restrict__ dinv,
        const float* __restrict__ W1, const float* __restrict__ b1,
        const float* __restrict__ W2, float* __restrict__ g2) {
    __shared__ float a0[8 * 256], a1[8 * 256];    // 16 KB
    int t = threadIdx.x, b = blockIdx.x, w = t >> 6;
#pragma unroll
    for (int k = 0; k < 4; ++k) { a0[k * SCT + t] = 0.0f; a1[k * SCT + t] = 0.0f; }
    __syncthreads();
    uint L = blen[b];
    const uint* p = part2 + (size_t)b * CAPB;
    for (uint i = t; i < L; i += SCT) {
        uint pk = p[i];
        float2 ys = y[pk >> 8];
        atomicAdd(&a0[w * 256 + (pk & 255u)], ys.x);
        atomicAdd(&a1[w * 256 + (pk & 255u)], ys.y);
    }
    __syncthreads();
    if (t < 256) {
        float A0 = 0.0f, A1 = 0.0f;
#pragma unroll
        for (int k = 0; k < 8; ++k) { A0 += a0[k * 256 + t]; A1 += a1[k * 256 + t]; }
        int node = (b << 8) + t;
        float di = dinv[node];
        float2 yn = y[node];
        A0 = di * (A0 + yn.x);                    // + self-loop, * dinv[d]
        A1 = di * (A1 + yn.y);
        float acc = 0.0f;
#pragma unroll
        for (int f = 0; f < F; ++f) {
            float v = fmaf(A0, W1[f], fmaf(A1, W1[F + f], b1[f]));
            acc = fmaf(fmaxf(v, 0.0f), W2[f], acc);
        }
        g2[node] = di * acc;
    }
}

// ---- layer 2: streaming bucket pass, wave-private bins + sigmoid -----------
__global__ void __launch_bounds__(SCT) k_l2(
        const uint* __restrict__ part2, const uint* __restrict__ blen,
        const float* __restrict__ g2, const float* __restrict__ dinv,
        const float* __restrict__ b2, float* __restrict__ scores) {
    __shared__ float a[8 * 256];                  // 8 KB
    int t = threadIdx.x, b = blockIdx.x, w = t >> 6;
#pragma unroll
    for (int k = 0; k < 4; ++k) a[k * SCT + t] = 0.0f;
    __syncthreads();
    uint L = blen[b];
    const uint* p = part2 + (size_t)b * CAPB;
    for (uint i = t; i < L; i += SCT) {
        uint pk = p[i];
        atomicAdd(&a[w * 256 + (pk & 255u)], g2[pk >> 8]);
    }
    __syncthreads();
    if (t < 256) {
        float acc = 0.0f;
#pragma unroll
        for (int k = 0; k < 8; ++k) acc += a[k * 256 + t];
        int node = (b << 8) + t;
        float v = fmaf(dinv[node], acc + g2[node], b2[0]);
        scores[node] = 1.0f / (1.0f + expf(-v));
    }
}

// ---- output gather: out[e] = scores[src[e]], 4 edges/thread ----------------
__global__ void k_out(const int* __restrict__ src, const float* __restrict__ scores,
                      float* __restrict__ out) {
    int i = blockIdx.x * blockDim.x + threadIdx.x;
    if (i >= E / 4) return;
    int4 s4 = ((const int4*)src)[i];
    float4 o;
    o.x = scores[s4.x];
    o.y = scores[s4.y];
    o.z = scores[s4.z];
    o.w = scores[s4.w];
    ((float4*)out)[i] = o;
}

extern "C" void kernel_launch(void* const* d_in, const int* in_sizes, int n_in,
                              void* d_out, int out_size, void* d_ws, size_t ws_size,
                              hipStream_t stream) {
    const float* x  = (const float*)d_in[0];   // [N,2]
    const float* W1 = (const float*)d_in[1];   // [2,16]
    const float* b1 = (const float*)d_in[2];   // [16]
    const float* W2 = (const float*)d_in[3];   // [16,1]
    const float* b2 = (const float*)d_in[4];   // [1]
    const int*   ei = (const int*)d_in[5];     // [2,E]
    const int* src = ei;
    const int* dst = ei + E;

    // ws: cnt16[256K u16] | dir16[256K u16] | blen[NB] | dinv[N] |
    //     y[N f32x2] | g2[N] | scores[N] | part2[NB*CAPB u32]   (~22.5 MB)
    u16* cnt16    = (u16*)d_ws;
    u16* dir16    = cnt16 + (size_t)NB * NBLK;
    uint* blen    = (uint*)(dir16 + (size_t)NB * NBLK);
    float* dinv   = (float*)(blen + NB);
    float2* y     = (float2*)(dinv + N);
    float* g2     = (float*)(y + N);
    float* scores = g2 + N;
    uint* part2   = (uint*)(scores + N);

    // block-grouped edges (16 MB) live in d_out; dead before k_out writes
    uint* part  = (uint*)d_out;
    float* out  = (float*)d_out;

    k_scatter<<<NBLK,        SCT, 0, stream>>>(src, dst, part, cnt16, dir16);
    k_gather <<<NB,          SCT, 0, stream>>>(part, cnt16, dir16, x, part2,
                                               blen, dinv, y);
    k_l1     <<<NB,          SCT, 0, stream>>>(part2, blen, y, dinv, W1, b1, W2, g2);
    k_l2     <<<NB,          SCT, 0, stream>>>(part2, blen, g2, dinv, b2, scores);
    k_out    <<<E / 4 / 256, 256, 0, stream>>>(src, scores, out);
}

// Round 11
// 176.265 us; speedup vs baseline: 1.1681x; 1.1681x over previous
//
#include <hip/hip_runtime.h>
#include <cmath>

typedef unsigned int uint;
typedef unsigned short u16;

constexpr int N  = 131072;    // nodes
constexpr int E  = 4194304;   // edges (without self-loops)
constexpr int F  = 16;        // hidden width H1
constexpr int NB = 512;       // dst buckets of 256 nodes (bucket = dst>>8)
constexpr int NBLK  = 512;    // scatter blocks
constexpr int SCT   = 512;    // threads per scatter/gather block
constexpr int CHUNK = 8192;   // edges per scatter block (NBLK*CHUNK == E)
constexpr int EPT   = 16;     // edges per thread in scatter
constexpr int CAPB  = 9216;   // padded per-bucket region (mean 8192, sd ~90 -> 11 sd)
constexpr int LT    = 1024;   // threads per l1/l2 block (16 waves)

// Fixed-point scales for native int LDS atomics (float LDS atomicAdd is a
// CAS loop on gfx9 — the r10 47µs/2%VALU signature).
constexpr float S1 = 4194304.0f;    // 2^22 for layer-1 sums (|y|<1, deg<=~64)
constexpr float S2 = 65536.0f;      // 2^16 for layer-2 sums (|g2|<~256)

// ---- Phase A: block-local bucket grouping, private regions, coalesced ------
__global__ void __launch_bounds__(SCT) k_scatter(
        const int* __restrict__ src, const int* __restrict__ dst,
        uint* __restrict__ part, u16* __restrict__ cnt16, u16* __restrict__ dir16) {
    __shared__ uint h[NB];          // hist -> bump counters
    __shared__ uint wsum[8];
    __shared__ uint vals[CHUNK];    // 32 KB staging
    int t = threadIdx.x, g = blockIdx.x;
    int lane = t & 63, w = t >> 6;
    h[t] = 0;
    __syncthreads();
    int d[EPT], s[EPT];
    const int4* src4 = (const int4*)src;
    const int4* dst4 = (const int4*)dst;
    int base4 = g * (CHUNK / 4);
#pragma unroll
    for (int k = 0; k < EPT / 4; ++k) {
        int4 d4 = dst4[base4 + k * SCT + t];
        int4 s4 = src4[base4 + k * SCT + t];
        d[4 * k + 0] = d4.x; d[4 * k + 1] = d4.y; d[4 * k + 2] = d4.z; d[4 * k + 3] = d4.w;
        s[4 * k + 0] = s4.x; s[4 * k + 1] = s4.y; s[4 * k + 2] = s4.z; s[4 * k + 3] = s4.w;
        atomicAdd(&h[d4.x >> 8], 1u);
        atomicAdd(&h[d4.y >> 8], 1u);
        atomicAdd(&h[d4.z >> 8], 1u);
        atomicAdd(&h[d4.w >> 8], 1u);
    }
    __syncthreads();
    uint v = h[t];
    uint sv = v;                                  // wave-level inclusive scan
#pragma unroll
    for (int off = 1; off < 64; off <<= 1) {
        uint n = __shfl_up(sv, off);
        if (lane >= off) sv += n;
    }
    if (lane == 63) wsum[w] = sv;
    __syncthreads();
    uint wo = 0;
    for (int i = 0; i < w; ++i) wo += wsum[i];
    sv += wo;                                     // inclusive over 512 buckets
    uint ex = sv - v;                             // local exclusive offset
    cnt16[(size_t)t * NBLK + g] = (u16)v;         // directory (bucket t, block g)
    dir16[(size_t)t * NBLK + g] = (u16)ex;
    __syncthreads();                              // all reads of h done
    h[t] = ex;                                    // bump starts at excl
    __syncthreads();
#pragma unroll
    for (int k = 0; k < EPT; ++k) {
        int b = d[k] >> 8;
        uint slot = atomicAdd(&h[b], 1u);
        vals[slot] = ((uint)s[k] << 8) | (uint)(d[k] & 255);
    }
    __syncthreads();
    uint4* part4 = (uint4*)(part + (size_t)g * CHUNK);
    const uint4* vals4 = (const uint4*)vals;
#pragma unroll
    for (int k = 0; k < EPT / 4; ++k)             // fully coalesced 16B stores
        part4[k * SCT + t] = vals4[k * SCT + t];
}

// ---- Phase B: coalesced directory gather -> part2 (bucket-contiguous), -----
// node degrees (native uint bins), dinv, y = dinv*x.
__global__ void __launch_bounds__(SCT) k_gather(
        const uint* __restrict__ part, const u16* __restrict__ cnt16,
        const u16* __restrict__ dir16, const float* __restrict__ x,
        uint* __restrict__ part2, uint* __restrict__ blen,
        float* __restrict__ dinv, float2* __restrict__ y) {
    __shared__ uint ps[NB + 1];     // exclusive prefix of segment lengths
    __shared__ uint segoff[NB];     // global offset of each segment
    __shared__ uint hw[8 * 256];    // wave-private node-bin counters (8 KB)
    __shared__ uint wsum[8];
    __shared__ uint stage[CAPB];    // 36 KB
    int t = threadIdx.x, b = blockIdx.x;
    int lane = t & 63, w = t >> 6;
#pragma unroll
    for (int k = 0; k < 4; ++k) hw[k * SCT + t] = 0;
    uint len = cnt16[(size_t)b * NBLK + t];
    segoff[t] = (uint)t * CHUNK + dir16[(size_t)b * NBLK + t];
    uint sv = len;                                // shfl inclusive scan
#pragma unroll
    for (int off = 1; off < 64; off <<= 1) {
        uint n = __shfl_up(sv, off);
        if (lane >= off) sv += n;
    }
    if (lane == 63) wsum[w] = sv;
    __syncthreads();
    uint wo = 0;
    for (int i = 0; i < w; ++i) wo += wsum[i];
    ps[t] = sv + wo - len;                        // exclusive prefix
    uint L = 0;
#pragma unroll
    for (int i = 0; i < 8; ++i) L += wsum[i];
    if (t == 0) ps[NB] = L;
    __syncthreads();
    for (uint i = t; i < L; i += SCT) {           // coalesced gather + count
        uint lo = 0, hi = NB;                     // find max s: ps[s] <= i
        while (hi - lo > 1) {
            uint mid = (lo + hi) >> 1;
            if (ps[mid] <= i) lo = mid; else hi = mid;
        }
        uint pk = part[segoff[lo] + (i - ps[lo])];
        if (i < (uint)CAPB) stage[i] = pk;
        atomicAdd(&hw[w * 256 + (pk & 255u)], 1u);
    }
    __syncthreads();
    uint Lc = (L > (uint)CAPB) ? (uint)CAPB : L;
    uint* o2 = part2 + (size_t)b * CAPB;
    for (uint i = t; i < Lc; i += SCT) o2[i] = stage[i];   // coalesced flush
    if (t == 0) blen[b] = Lc;
    if (t < 256) {
        uint c = 0;
#pragma unroll
        for (int k = 0; k < 8; ++k) c += hw[k * 256 + t];
        int node = (b << 8) + t;
        float di = rsqrtf(1.0f + (float)c);       // +1 self-loop
        dinv[node] = di;
        float2 xv = ((const float2*)x)[node];
        y[node] = make_float2(di * xv.x, di * xv.y);
    }
}

// ---- layer 1: streaming bucket pass, NATIVE int LDS bins + fused MLP -------
__global__ void __launch_bounds__(LT) k_l1(
        const uint* __restrict__ part2, const uint* __restrict__ blen,
        const float2* __restrict__ y, const float* __restrict__ dinv,
        const float* __restrict__ W1, const float* __restrict__ b1,
        const float* __restrict__ W2, float* __restrict__ g2) {
    __shared__ int a0[16 * 256], a1[16 * 256];    // 32 KB, wave-private
    int t = threadIdx.x, b = blockIdx.x, w = t >> 6;
#pragma unroll
    for (int k = 0; k < 4; ++k) { a0[k * LT + t] = 0; a1[k * LT + t] = 0; }
    __syncthreads();
    uint L = blen[b];
    const uint* p = part2 + (size_t)b * CAPB;
    for (uint i = t; i < L; i += LT) {
        uint pk = p[i];
        float2 ys = y[pk >> 8];
        atomicAdd(&a0[w * 256 + (pk & 255u)], __float2int_rn(ys.x * S1));
        atomicAdd(&a1[w * 256 + (pk & 255u)], __float2int_rn(ys.y * S1));
    }
    __syncthreads();
    if (t < 256) {
        int s0 = 0, s1 = 0;
#pragma unroll
        for (int k = 0; k < 16; ++k) { s0 += a0[k * 256 + t]; s1 += a1[k * 256 + t]; }
        int node = (b << 8) + t;
        float di = dinv[node];
        float2 yn = y[node];
        float A0 = di * ((float)s0 * (1.0f / S1) + yn.x);   // + self-loop
        float A1 = di * ((float)s1 * (1.0f / S1) + yn.y);
        float acc = 0.0f;
#pragma unroll
        for (int f = 0; f < F; ++f) {
            float v = fmaf(A0, W1[f], fmaf(A1, W1[F + f], b1[f]));
            acc = fmaf(fmaxf(v, 0.0f), W2[f], acc);
        }
        g2[node] = di * acc;
    }
}

// ---- layer 2: streaming bucket pass, NATIVE int LDS bins + sigmoid ---------
__global__ void __launch_bounds__(LT) k_l2(
        const uint* __restrict__ part2, const uint* __restrict__ blen,
        const float* __restrict__ g2, const float* __restrict__ dinv,
        const float* __restrict__ b2, float* __restrict__ scores) {
    __shared__ int a[16 * 256];                   // 16 KB, wave-private
    int t = threadIdx.x, b = blockIdx.x, w = t >> 6;
#pragma unroll
    for (int k = 0; k < 4; ++k) a[k * LT + t] = 0;
    __syncthreads();
    uint L = blen[b];
    const uint* p = part2 + (size_t)b * CAPB;
    for (uint i = t; i < L; i += LT) {
        uint pk = p[i];
        atomicAdd(&a[w * 256 + (pk & 255u)], __float2int_rn(g2[pk >> 8] * S2));
    }
    __syncthreads();
    if (t < 256) {
        int s = 0;
#pragma unroll
        for (int k = 0; k < 16; ++k) s += a[k * 256 + t];
        int node = (b << 8) + t;
        float acc = (float)s * (1.0f / S2);
        float v = fmaf(dinv[node], acc + g2[node], b2[0]);
        scores[node] = 1.0f / (1.0f + expf(-v));
    }
}

// ---- output gather: out[e] = scores[src[e]], 4 edges/thread ----------------
__global__ void k_out(const int* __restrict__ src, const float* __restrict__ scores,
                      float* __restrict__ out) {
    int i = blockIdx.x * blockDim.x + threadIdx.x;
    if (i >= E / 4) return;
    int4 s4 = ((const int4*)src)[i];
    float4 o;
    o.x = scores[s4.x];
    o.y = scores[s4.y];
    o.z = scores[s4.z];
    o.w = scores[s4.w];
    ((float4*)out)[i] = o;
}

extern "C" void kernel_launch(void* const* d_in, const int* in_sizes, int n_in,
                              void* d_out, int out_size, void* d_ws, size_t ws_size,
                              hipStream_t stream) {
    const float* x  = (const float*)d_in[0];   // [N,2]
    const float* W1 = (const float*)d_in[1];   // [2,16]
    const float* b1 = (const float*)d_in[2];   // [16]
    const float* W2 = (const float*)d_in[3];   // [16,1]
    const float* b2 = (const float*)d_in[4];   // [1]
    const int*   ei = (const int*)d_in[5];     // [2,E]
    const int* src = ei;
    const int* dst = ei + E;

    // ws: cnt16[256K u16] | dir16[256K u16] | blen[NB] | dinv[N] |
    //     y[N f32x2] | g2[N] | scores[N] | part2[NB*CAPB u32]   (~22.5 MB)
    u16* cnt16    = (u16*)d_ws;
    u16* dir16    = cnt16 + (size_t)NB * NBLK;
    uint* blen    = (uint*)(dir16 + (size_t)NB * NBLK);
    float* dinv   = (float*)(blen + NB);
    float2* y     = (float2*)(dinv + N);
    float* g2     = (float*)(y + N);
    float* scores = g2 + N;
    uint* part2   = (uint*)(scores + N);

    // block-grouped edges (16 MB) live in d_out; dead before k_out writes
    uint* part  = (uint*)d_out;
    float* out  = (float*)d_out;

    k_scatter<<<NBLK,        SCT, 0, stream>>>(src, dst, part, cnt16, dir16);
    k_gather <<<NB,          SCT, 0, stream>>>(part, cnt16, dir16, x, part2,
                                               blen, dinv, y);
    k_l1     <<<NB,          LT,  0, stream>>>(part2, blen, y, dinv, W1, b1, W2, g2);
    k_l2     <<<NB,          LT,  0, stream>>>(part2, blen, g2, dinv, b2, scores);
    k_out    <<<E / 4 / 256, 256, 0, stream>>>(src, scores, out);
}

// Round 12
// 168.363 us; speedup vs baseline: 1.2229x; 1.0469x over previous
//
#include <hip/hip_runtime.h>
#include <cmath>

typedef unsigned int uint;

constexpr int N  = 131072;    // nodes
constexpr int E  = 4194304;   // edges (without self-loops)
constexpr int F  = 16;        // hidden width H1
constexpr int NB = 512;       // dst buckets of 256 nodes (bucket = dst>>8)
constexpr int NBLK  = 512;    // scatter blocks
constexpr int SCT   = 512;    // threads per scatter block
constexpr int GT    = 1024;   // threads per gather block (16 waves)
constexpr int CHUNK = 8192;   // edges per scatter block (NBLK*CHUNK == E)
constexpr int EPT   = 16;     // edges per thread in scatter
constexpr int CAPB  = 9216;   // padded per-bucket region (mean 8192, sd ~90; %4==0)
constexpr int LT    = 1024;   // threads per l1/l2 block (16 waves)
constexpr uint SENT = 0xFFFFFFFFu;   // pad sentinel edge

// Fixed-point scales for native int LDS atomics (float LDS atomicAdd is a
// CAS loop on gfx9 — the r10 47µs/2%VALU signature; r11 confirmed the fix).
constexpr float S1 = 4194304.0f;    // 2^22 for layer-1 sums (|y|<1, deg<=~64)
constexpr float S2 = 65536.0f;      // 2^16 for layer-2 sums (|g2| small)

// ---- Phase A: block-local bucket grouping, private regions, coalesced ------
// Directory entry (u32): low16 = count of bucket b in block g, high16 = local
// offset of that run. Stored COALESCED at dirw[g*NB + b]; k_tr transposes.
__global__ void __launch_bounds__(SCT) k_scatter(
        const int* __restrict__ src, const int* __restrict__ dst,
        uint* __restrict__ part, uint* __restrict__ dirw) {
    __shared__ uint h[NB];          // hist -> bump counters
    __shared__ uint wsum[8];
    __shared__ uint vals[CHUNK];    // 32 KB staging
    int t = threadIdx.x, g = blockIdx.x;
    int lane = t & 63, w = t >> 6;
    h[t] = 0;
    __syncthreads();
    int d[EPT], s[EPT];
    const int4* src4 = (const int4*)src;
    const int4* dst4 = (const int4*)dst;
    int base4 = g * (CHUNK / 4);
#pragma unroll
    for (int k = 0; k < EPT / 4; ++k) {
        int4 d4 = dst4[base4 + k * SCT + t];
        int4 s4 = src4[base4 + k * SCT + t];
        d[4 * k + 0] = d4.x; d[4 * k + 1] = d4.y; d[4 * k + 2] = d4.z; d[4 * k + 3] = d4.w;
        s[4 * k + 0] = s4.x; s[4 * k + 1] = s4.y; s[4 * k + 2] = s4.z; s[4 * k + 3] = s4.w;
        atomicAdd(&h[d4.x >> 8], 1u);
        atomicAdd(&h[d4.y >> 8], 1u);
        atomicAdd(&h[d4.z >> 8], 1u);
        atomicAdd(&h[d4.w >> 8], 1u);
    }
    __syncthreads();
    uint v = h[t];
    uint sv = v;                                  // wave-level inclusive scan
#pragma unroll
    for (int off = 1; off < 64; off <<= 1) {
        uint n = __shfl_up(sv, off);
        if (lane >= off) sv += n;
    }
    if (lane == 63) wsum[w] = sv;
    __syncthreads();
    uint wo = 0;
    for (int i = 0; i < w; ++i) wo += wsum[i];
    sv += wo;                                     // inclusive over 512 buckets
    uint ex = sv - v;                             // local exclusive offset
    dirw[(size_t)g * NB + t] = v | (ex << 16);    // coalesced directory store
    __syncthreads();                              // all reads of h done
    h[t] = ex;                                    // bump starts at excl
    __syncthreads();
#pragma unroll
    for (int k = 0; k < EPT; ++k) {
        int b = d[k] >> 8;
        uint slot = atomicAdd(&h[b], 1u);
        vals[slot] = ((uint)s[k] << 8) | (uint)(d[k] & 255);
    }
    __syncthreads();
    uint4* part4 = (uint4*)(part + (size_t)g * CHUNK);
    const uint4* vals4 = (const uint4*)vals;
#pragma unroll
    for (int k = 0; k < EPT / 4; ++k)             // fully coalesced 16B stores
        part4[k * SCT + t] = vals4[k * SCT + t];
}

// ---- directory transpose: [g][b] -> [b][g], LDS tile, coalesced both sides -
__global__ void k_tr(const uint* __restrict__ in, uint* __restrict__ outm) {
    __shared__ uint tile[32][33];
    int bx = blockIdx.x, by = blockIdx.y;         // 16 x 16
    int tx = threadIdx.x, ty = threadIdx.y;       // 32 x 32
    tile[ty][tx] = in[(size_t)(by * 32 + ty) * NB + bx * 32 + tx];
    __syncthreads();
    outm[(size_t)(bx * 32 + ty) * NBLK + by * 32 + tx] = tile[tx][ty];
}

// ---- Phase B: coalesced directory gather -> part2 (bucket-contiguous), -----
// node degrees (native uint bins), dinv, y = dinv*x. 1024 threads.
__global__ void __launch_bounds__(GT) k_gather(
        const uint* __restrict__ part, const uint* __restrict__ dirT,
        const float* __restrict__ x,
        uint* __restrict__ part2, uint* __restrict__ blen,
        float* __restrict__ dinv, float2* __restrict__ y) {
    __shared__ uint ps[NB + 1];     // exclusive prefix of segment lengths
    __shared__ uint segoff[NB];     // global offset of each segment
    __shared__ uint hw[16 * 256];   // wave-private node-bin counters (16 KB)
    __shared__ uint wsum[8];
    __shared__ uint stage[CAPB];    // 36 KB
    int t = threadIdx.x, b = blockIdx.x;
    int lane = t & 63, w = t >> 6;
#pragma unroll
    for (int k = 0; k < 4; ++k) hw[k * GT + t] = 0;
    if (t < NB) {
        uint pd = dirT[(size_t)b * NBLK + t];     // coalesced packed directory
        uint len = pd & 0xFFFFu;
        segoff[t] = (uint)t * CHUNK + (pd >> 16);
        uint sv = len;                            // shfl inclusive scan (8 waves)
#pragma unroll
        for (int off = 1; off < 64; off <<= 1) {
            uint n = __shfl_up(sv, off);
            if (lane >= off) sv += n;
        }
        if (lane == 63) wsum[w] = sv;
        ps[t] = sv - len;                         // partial (pre cross-wave)
    }
    __syncthreads();
    if (t < NB) {
        uint wo = 0;
        for (int i = 0; i < w; ++i) wo += wsum[i];
        ps[t] += wo;
    }
    if (t == 0) {
        uint L = 0;
#pragma unroll
        for (int i = 0; i < 8; ++i) L += wsum[i];
        ps[NB] = L;
    }
    __syncthreads();
    uint L = ps[NB];
    for (uint i = t; i < L; i += GT) {            // coalesced gather + count
        uint lo = 0, hi = NB;                     // find max s: ps[s] <= i
        while (hi - lo > 1) {
            uint mid = (lo + hi) >> 1;
            if (ps[mid] <= i) lo = mid; else hi = mid;
        }
        uint pk = part[segoff[lo] + (i - ps[lo])];
        if (i < (uint)CAPB) stage[i] = pk;
        atomicAdd(&hw[w * 256 + (pk & 255u)], 1u);
    }
    __syncthreads();
    uint Lc = (L > (uint)CAPB) ? (uint)CAPB : L;
    uint Lp = (Lc + 3u) & ~3u;                    // pad to x4 for uint4 readers
    uint* o2 = part2 + (size_t)b * CAPB;
    for (uint i = t; i < Lp; i += GT) o2[i] = (i < Lc) ? stage[i] : SENT;
    if (t == 0) blen[b] = Lp;
    if (t < 256) {
        uint c = 0;
#pragma unroll
        for (int k = 0; k < 16; ++k) c += hw[k * 256 + t];
        int node = (b << 8) + t;
        float di = rsqrtf(1.0f + (float)c);       // +1 self-loop
        dinv[node] = di;
        float2 xv = ((const float2*)x)[node];
        y[node] = make_float2(di * xv.x, di * xv.y);
    }
}

// ---- layer 1: uint4 streaming, native int LDS bins + fused MLP -------------
__global__ void __launch_bounds__(LT) k_l1(
        const uint* __restrict__ part2, const uint* __restrict__ blen,
        const float2* __restrict__ y, const float* __restrict__ dinv,
        const float* __restrict__ W1, const float* __restrict__ b1,
        const float* __restrict__ W2, float* __restrict__ g2) {
    __shared__ int a0[16 * 256], a1[16 * 256];    // 32 KB, wave-private
    int t = threadIdx.x, b = blockIdx.x, w = t >> 6;
#pragma unroll
    for (int k = 0; k < 4; ++k) { a0[k * LT + t] = 0; a1[k * LT + t] = 0; }
    __syncthreads();
    uint L4 = blen[b] >> 2;
    const uint4* p4 = (const uint4*)(part2 + (size_t)b * CAPB);
    for (uint i = t; i < L4; i += LT) {
        uint4 q = p4[i];
        uint pk;
#pragma unroll
        for (int k = 0; k < 4; ++k) {
            pk = (k == 0) ? q.x : (k == 1) ? q.y : (k == 2) ? q.z : q.w;
            if (pk != SENT) {
                float2 ys = y[pk >> 8];
                atomicAdd(&a0[w * 256 + (pk & 255u)], __float2int_rn(ys.x * S1));
                atomicAdd(&a1[w * 256 + (pk & 255u)], __float2int_rn(ys.y * S1));
            }
        }
    }
    __syncthreads();
    if (t < 256) {
        int s0 = 0, s1 = 0;
#pragma unroll
        for (int k = 0; k < 16; ++k) { s0 += a0[k * 256 + t]; s1 += a1[k * 256 + t]; }
        int node = (b << 8) + t;
        float di = dinv[node];
        float2 yn = y[node];
        float A0 = di * ((float)s0 * (1.0f / S1) + yn.x);   // + self-loop
        float A1 = di * ((float)s1 * (1.0f / S1) + yn.y);
        float acc = 0.0f;
#pragma unroll
        for (int f = 0; f < F; ++f) {
            float v = fmaf(A0, W1[f], fmaf(A1, W1[F + f], b1[f]));
            acc = fmaf(fmaxf(v, 0.0f), W2[f], acc);
        }
        g2[node] = di * acc;
    }
}

// ---- layer 2: uint4 streaming, native int LDS bins + sigmoid ---------------
__global__ void __launch_bounds__(LT) k_l2(
        const uint* __restrict__ part2, const uint* __restrict__ blen,
        const float* __restrict__ g2, const float* __restrict__ dinv,
        const float* __restrict__ b2, float* __restrict__ scores) {
    __shared__ int a[16 * 256];                   // 16 KB, wave-private
    int t = threadIdx.x, b = blockIdx.x, w = t >> 6;
#pragma unroll
    for (int k = 0; k < 4; ++k) a[k * LT + t] = 0;
    __syncthreads();
    uint L4 = blen[b] >> 2;
    const uint4* p4 = (const uint4*)(part2 + (size_t)b * CAPB);
    for (uint i = t; i < L4; i += LT) {
        uint4 q = p4[i];
        uint pk;
#pragma unroll
        for (int k = 0; k < 4; ++k) {
            pk = (k == 0) ? q.x : (k == 1) ? q.y : (k == 2) ? q.z : q.w;
            if (pk != SENT)
                atomicAdd(&a[w * 256 + (pk & 255u)], __float2int_rn(g2[pk >> 8] * S2));
        }
    }
    __syncthreads();
    if (t < 256) {
        int s = 0;
#pragma unroll
        for (int k = 0; k < 16; ++k) s += a[k * 256 + t];
        int node = (b << 8) + t;
        float acc = (float)s * (1.0f / S2);
        float v = fmaf(dinv[node], acc + g2[node], b2[0]);
        scores[node] = 1.0f / (1.0f + expf(-v));
    }
}

// ---- output gather: out[e] = scores[src[e]], 4 edges/thread ----------------
__global__ void k_out(const int* __restrict__ src, const float* __restrict__ scores,
                      float* __restrict__ out) {
    int i = blockIdx.x * blockDim.x + threadIdx.x;
    if (i >= E / 4) return;
    int4 s4 = ((const int4*)src)[i];
    float4 o;
    o.x = scores[s4.x];
    o.y = scores[s4.y];
    o.z = scores[s4.z];
    o.w = scores[s4.w];
    ((float4*)out)[i] = o;
}

extern "C" void kernel_launch(void* const* d_in, const int* in_sizes, int n_in,
                              void* d_out, int out_size, void* d_ws, size_t ws_size,
                              hipStream_t stream) {
    const float* x  = (const float*)d_in[0];   // [N,2]
    const float* W1 = (const float*)d_in[1];   // [2,16]
    const float* b1 = (const float*)d_in[2];   // [16]
    const float* W2 = (const float*)d_in[3];   // [16,1]
    const float* b2 = (const float*)d_in[4];   // [1]
    const int*   ei = (const int*)d_in[5];     // [2,E]
    const int* src = ei;
    const int* dst = ei + E;

    // ws: dirw[512*512 u32] | dirT[512*512 u32] | blen[NB] | dinv[N] |
    //     y[N f32x2] | g2[N] | scores[N] | part2[NB*CAPB u32]   (~23.5 MB)
    uint* dirw    = (uint*)d_ws;
    uint* dirT    = dirw + (size_t)NBLK * NB;
    uint* blen    = dirT + (size_t)NBLK * NB;
    float* dinv   = (float*)(blen + NB);
    float2* y     = (float2*)(dinv + N);
    float* g2     = (float*)(y + N);
    float* scores = g2 + N;
    uint* part2   = (uint*)(scores + N);

    // block-grouped edges (16 MB) live in d_out; dead before k_out writes
    uint* part  = (uint*)d_out;
    float* out  = (float*)d_out;

    k_scatter<<<NBLK,              SCT,           0, stream>>>(src, dst, part, dirw);
    k_tr     <<<dim3(16, 16),      dim3(32, 32),  0, stream>>>(dirw, dirT);
    k_gather <<<NB,                GT,            0, stream>>>(part, dirT, x, part2,
                                                               blen, dinv, y);
    k_l1     <<<NB,                LT,            0, stream>>>(part2, blen, y, dinv,
                                                               W1, b1, W2, g2);
    k_l2     <<<NB,                LT,            0, stream>>>(part2, blen, g2, dinv,
                                                               b2, scores);
    k_out    <<<E / 4 / 256,       256,           0, stream>>>(src, scores, out);
}